// Round 6
// baseline (650.052 us; speedup 1.0000x reference)
//
#include <hip/hip_runtime.h>
#include <stdint.h>
#include <stddef.h>

// Problem constants
#define B_    16
#define N_SEQ 4096
#define C_    512
#define H_    8
#define E_    64
#define M_TOT (B_ * N_SEQ)   // 65536
#define QKVN  (3 * C_)       // 1536

typedef __attribute__((ext_vector_type(8))) short short8;
typedef __attribute__((ext_vector_type(4))) short s16x4;
typedef __attribute__((ext_vector_type(4))) float f32x4;

__device__ __forceinline__ unsigned short f2bf(float f) {
  uint32_t u = __builtin_bit_cast(uint32_t, f);
  return (unsigned short)((u + 0x7fffu + ((u >> 16) & 1u)) >> 16);  // RNE
}
__device__ __forceinline__ float bf2f(unsigned short h) {
  uint32_t u = ((uint32_t)h) << 16;
  return __builtin_bit_cast(float, u);
}

// ---------------------------------------------------------------- convert
__global__ __launch_bounds__(256) void cvt_bf16(const float* __restrict__ in,
                                                unsigned short* __restrict__ out) {
  size_t i = ((size_t)blockIdx.x * 256 + threadIdx.x) * 8;
  float4 a = *(const float4*)(in + i);
  float4 b = *(const float4*)(in + i + 4);
  short8 o;
  o[0] = (short)f2bf(a.x); o[1] = (short)f2bf(a.y);
  o[2] = (short)f2bf(a.z); o[3] = (short)f2bf(a.w);
  o[4] = (short)f2bf(b.x); o[5] = (short)f2bf(b.y);
  o[6] = (short)f2bf(b.z); o[7] = (short)f2bf(b.w);
  *(short8*)(out + i) = o;
}

// ---------------------------------------------------------------- GEMM (C = A * B^T), bf16 in, f32 accum
// LDS-FREE: every MFMA fragment is 8 contiguous bf16 of a global row
// (addr = row*K + kt*32 + fg*8). Lanes {fr,fr+16,fr+32,fr+48} read consecutive
// 16B chunks -> each global_load_dwordx4 is 16x coalesced 64B segments.
// Fragments stream global->VGPR with a register double-buffer (no barriers,
// no LDS bank conflicts). Reuse is served by L1/L2 (B-panel is L2-resident;
// A-panel reused across NT col-tiles on the same XCD via the bid swizzle).
// MODE 1: qkv epilogue -> bf16 store, relu+0.125 on cols < 1024 (q,k); ksum for k cols
// MODE 2: f32 store + bias
template <int MODE>
__global__ __launch_bounds__(256) void gemm_bt(
    const unsigned short* __restrict__ A, const unsigned short* __restrict__ Bm,
    void* __restrict__ Cout, const float* __restrict__ bias,
    float* __restrict__ ksum, int M, int N, int K, int NT) {
  // XCD-aware swizzle (grid % 8 == 0): contiguous tile ranges per XCD
  const int nwg = gridDim.x;
  const int q8 = nwg >> 3;
  int bid = blockIdx.x;
  bid = (bid & 7) * q8 + (bid >> 3);
  const int mt = bid / NT, nt = bid - mt * NT;
  const int row0 = mt << 7, col0 = nt << 7;
  const int tid = threadIdx.x;
  const int lane = tid & 63, wave = tid >> 6;
  const int wm = (wave & 1) << 6, wn = (wave >> 1) << 6;
  const int fr = lane & 15, fg = lane >> 4;

  const unsigned short* pa = A + (size_t)(row0 + wm + fr) * K + fg * 8;
  const unsigned short* pb = Bm + (size_t)(col0 + wn + fr) * K + fg * 8;
  const size_t rstep = (size_t)16 * K;  // 16 rows

  f32x4 acc[4][4] = {};
  short8 a0[4], b0[4], a1[4], b1[4];

#define LDFRAG(dst, p, i, kt) dst[i] = *(const short8*)((p) + (size_t)(i)*rstep + (kt) * 32)

#pragma unroll
  for (int i = 0; i < 4; i++) { LDFRAG(a0, pa, i, 0); LDFRAG(b0, pb, i, 0); }

  const int NKT = K >> 5;  // 16 for K=512
#pragma unroll
  for (int kt = 0; kt < 16; kt += 2) {
    if (kt + 1 < NKT) {
#pragma unroll
      for (int i = 0; i < 4; i++) { LDFRAG(a1, pa, i, kt + 1); LDFRAG(b1, pb, i, kt + 1); }
    }
#pragma unroll
    for (int i = 0; i < 4; i++)
#pragma unroll
      for (int j = 0; j < 4; j++)
        acc[i][j] = __builtin_amdgcn_mfma_f32_16x16x32_bf16(a0[i], b0[j], acc[i][j], 0, 0, 0);
    if (kt + 2 < NKT) {
#pragma unroll
      for (int i = 0; i < 4; i++) { LDFRAG(a0, pa, i, kt + 2); LDFRAG(b0, pb, i, kt + 2); }
    }
#pragma unroll
    for (int i = 0; i < 4; i++)
#pragma unroll
      for (int j = 0; j < 4; j++)
        acc[i][j] = __builtin_amdgcn_mfma_f32_16x16x32_bf16(a1[i], b1[j], acc[i][j], 0, 0, 0);
  }
#undef LDFRAG

  if (MODE == 1) {
    unsigned short* Cq = (unsigned short*)Cout;
    const bool isk = (col0 >= C_) && (col0 < 2 * C_);
    float ksp[4] = {0.f, 0.f, 0.f, 0.f};
#pragma unroll
    for (int i = 0; i < 4; i++) {
      const int r0 = row0 + wm + i * 16 + fg * 4;
#pragma unroll
      for (int j = 0; j < 4; j++) {
        const int c = col0 + wn + j * 16 + fr;
        const bool qk = (c < 2 * C_);
#pragma unroll
        for (int r = 0; r < 4; r++) {
          float v = acc[i][j][r];
          if (qk) v = fmaxf(v, 0.0f) + 0.125f;   // relu + E^-0.5
          if (isk) ksp[j] += v;
          Cq[(size_t)(r0 + r) * N + c] = f2bf(v);
        }
      }
    }
    if (isk) {
      const int b = row0 >> 12;
#pragma unroll
      for (int j = 0; j < 4; j++) {
        float s = ksp[j];
        s += __shfl_xor(s, 16, 64);
        s += __shfl_xor(s, 32, 64);
        if (lane < 16) {
          const int cc = col0 + wn + j * 16 + lane - C_;  // 0..511
          atomicAdd(&ksum[(size_t)((b << 3) + (cc >> 6)) * 64 + (cc & 63)], s);
        }
      }
    }
  } else {
    float* Cf = (float*)Cout;
#pragma unroll
    for (int i = 0; i < 4; i++) {
      const int r0 = row0 + wm + i * 16 + fg * 4;
#pragma unroll
      for (int j = 0; j < 4; j++) {
        const int c = col0 + wn + j * 16 + fr;
        const float bb = bias[c];
#pragma unroll
        for (int r = 0; r < 4; r++)
          Cf[(size_t)(r0 + r) * N + c] = acc[i][j][r] + bb;
      }
    }
  }
}

// ---------------------------------------------------------------- KV^T via MFMA
// KVT[bh][f][e] += sum_{n in chunk} v[n][f] * k_[n][e]
// grid: 128 bh * 8 chunks; block 256 (4 waves); wave w owns f-rows [16w,16w+16)
__global__ __launch_bounds__(256) void kv_mfma(const unsigned short* __restrict__ qkv,
                                               float* __restrict__ KVT) {
  const int bid = blockIdx.x;
  const int ch = bid & 7, bh = bid >> 3;
  const int h = bh & 7, b = bh >> 3;
  const int n0 = ch << 9;  // 512-row chunk
  __shared__ unsigned short ktile[64][68];
  __shared__ unsigned short vtile[64][68];
  const int tid = threadIdx.x;
  const int lane = tid & 63, w = tid >> 6;
  const int fr = lane & 15, fg = lane >> 4;
  const int srow = tid >> 3;            // 0..31
  const int sseg = (tid & 7) << 3;      // 0..56 step 8
  const unsigned short* gk = qkv + (size_t)(b * N_SEQ + n0 + srow) * QKVN + C_ + h * E_ + sseg;
  const unsigned short* gv = gk + C_;   // v is +512 elems within the row

  f32x4 acc[4] = {};
  short8 pk0, pk1, pv0, pv1;
  pk0 = *(const short8*)gk;
  pk1 = *(const short8*)(gk + (size_t)32 * QKVN);
  pv0 = *(const short8*)gv;
  pv1 = *(const short8*)(gv + (size_t)32 * QKVN);

  for (int it = 0; it < 8; ++it) {
    {
      s16x4* dk0 = (s16x4*)&ktile[srow][sseg];
      s16x4* dk1 = (s16x4*)&ktile[srow + 32][sseg];
      s16x4* dv0 = (s16x4*)&vtile[srow][sseg];
      s16x4* dv1 = (s16x4*)&vtile[srow + 32][sseg];
      const s16x4* s;
      s = (const s16x4*)&pk0; dk0[0] = s[0]; dk0[1] = s[1];
      s = (const s16x4*)&pk1; dk1[0] = s[0]; dk1[1] = s[1];
      s = (const s16x4*)&pv0; dv0[0] = s[0]; dv0[1] = s[1];
      s = (const s16x4*)&pv1; dv1[0] = s[0]; dv1[1] = s[1];
    }
    __syncthreads();
    if (it < 7) {
      const unsigned short* nk = gk + (size_t)(it + 1) * 64 * QKVN;
      const unsigned short* nv = gv + (size_t)(it + 1) * 64 * QKVN;
      pk0 = *(const short8*)nk;
      pk1 = *(const short8*)(nk + (size_t)32 * QKVN);
      pv0 = *(const short8*)nv;
      pv1 = *(const short8*)(nv + (size_t)32 * QKVN);
    }
#pragma unroll
    for (int ks = 0; ks < 2; ++ks) {
      const int kb = ks * 32;
      short8 av, bk0, bk1, bk2, bk3;
#pragma unroll
      for (int j = 0; j < 8; ++j) {
        const int row = kb + fg * 8 + j;
        av[j]  = (short)vtile[row][w * 16 + fr];
        bk0[j] = (short)ktile[row][fr];
        bk1[j] = (short)ktile[row][16 + fr];
        bk2[j] = (short)ktile[row][32 + fr];
        bk3[j] = (short)ktile[row][48 + fr];
      }
      acc[0] = __builtin_amdgcn_mfma_f32_16x16x32_bf16(av, bk0, acc[0], 0, 0, 0);
      acc[1] = __builtin_amdgcn_mfma_f32_16x16x32_bf16(av, bk1, acc[1], 0, 0, 0);
      acc[2] = __builtin_amdgcn_mfma_f32_16x16x32_bf16(av, bk2, acc[2], 0, 0, 0);
      acc[3] = __builtin_amdgcn_mfma_f32_16x16x32_bf16(av, bk3, acc[3], 0, 0, 0);
    }
    __syncthreads();
  }

  const size_t fbase = (size_t)bh * 64 + w * 16 + fg * 4;
#pragma unroll
  for (int e = 0; e < 4; ++e)
#pragma unroll
    for (int r = 0; r < 4; ++r)
      atomicAdd(&KVT[(fbase + r) * 64 + e * 16 + fr], acc[e][r]);
}

// ---------------------------------------------------------------- attention output
__global__ __launch_bounds__(256) void attn_out(const unsigned short* __restrict__ qkv,
                                                const float* __restrict__ KVT,
                                                const float* __restrict__ ksum,
                                                unsigned short* __restrict__ hout) {
  const int bid = blockIdx.x;
  const int nc = bid & 63, bh = bid >> 6;
  const int h = bh & 7, b = bh >> 3;
  const int n0 = nc << 6;  // 64-row chunk
  __shared__ float qs[64][68];
  __shared__ float denp[64][4];
  __shared__ float zl[64];
  __shared__ float kss[64];
  const int t = threadIdx.x;

#pragma unroll
  for (int half = 0; half < 2; half++) {
    const int row = (t >> 3) + half * 32;
    const int e0 = (t & 7) * 8;
    const unsigned short* srcq = qkv + (size_t)(b * N_SEQ + n0 + row) * QKVN + h * E_ + e0;
    short8 raw = *(const short8*)srcq;
#pragma unroll
    for (int i = 0; i < 8; i++) qs[row][e0 + i] = bf2f((unsigned short)raw[i]);
  }
  if (t < 64) kss[t] = ksum[bh * 64 + t];
  __syncthreads();

  {
    const int r = t >> 2, qp = t & 3;
    float s = 0.f;
#pragma unroll
    for (int e = 0; e < 16; e++) s = fmaf(qs[r][qp * 16 + e], kss[qp * 16 + e], s);
    denp[r][qp] = s;
  }
  __syncthreads();
  if (t < 64) zl[t] = 1.0f / (denp[t][0] + denp[t][1] + denp[t][2] + denp[t][3] + 1e-6f);
  __syncthreads();

  const int f = t & 63, rg = t >> 6;
  float kvc[64];
  const float* kvp = KVT + (size_t)bh * 4096 + (size_t)f * 64;
#pragma unroll
  for (int i = 0; i < 16; i++) {
    float4 v4 = *(const float4*)(kvp + i * 4);
    kvc[4 * i] = v4.x; kvc[4 * i + 1] = v4.y; kvc[4 * i + 2] = v4.z; kvc[4 * i + 3] = v4.w;
  }
#pragma unroll
  for (int i = 0; i < 16; i++) {
    const int row = rg * 16 + i;
    float a = 0.f;
#pragma unroll
    for (int e4 = 0; e4 < 16; e4++) {
      float4 qv = *(const float4*)&qs[row][e4 * 4];
      a = fmaf(qv.x, kvc[4 * e4 + 0], a);
      a = fmaf(qv.y, kvc[4 * e4 + 1], a);
      a = fmaf(qv.z, kvc[4 * e4 + 2], a);
      a = fmaf(qv.w, kvc[4 * e4 + 3], a);
    }
    const float val = a * zl[row];
    hout[(size_t)(b * N_SEQ + n0 + row) * C_ + h * E_ + f] = f2bf(val);
  }
}

// ---------------------------------------------------------------- launcher
extern "C" void kernel_launch(void* const* d_in, const int* in_sizes, int n_in,
                              void* d_out, int out_size, void* d_ws, size_t ws_size,
                              hipStream_t stream) {
  const float* x  = (const float*)d_in[0];
  const float* wq = (const float*)d_in[1];
  const float* wp = (const float*)d_in[2];
  const float* bp = (const float*)d_in[3];
  float* out = (float*)d_out;

  char* ws = (char*)d_ws;
  const size_t SZ_XBF  = (size_t)M_TOT * C_ * 2;      //  67108864
  const size_t SZ_QKV  = (size_t)M_TOT * QKVN * 2;    // 201326592
  const size_t SZ_WQ   = (size_t)QKVN * C_ * 2;       //   1572864
  const size_t SZ_WP   = (size_t)C_ * C_ * 2;         //    524288
  const size_t SZ_KVT  = (size_t)128 * 64 * 64 * 4;   //   2097152
  unsigned short* x_bf   = (unsigned short*)(ws);
  unsigned short* qkv_bf = (unsigned short*)(ws + SZ_XBF);
  unsigned short* wq_bf  = (unsigned short*)(ws + SZ_XBF + SZ_QKV);
  unsigned short* wp_bf  = (unsigned short*)(ws + SZ_XBF + SZ_QKV + SZ_WQ);
  float* KVT   = (float*)(ws + SZ_XBF + SZ_QKV + SZ_WQ + SZ_WP);
  float* ksumb = (float*)(ws + SZ_XBF + SZ_QKV + SZ_WQ + SZ_WP + SZ_KVT);
  unsigned short* hout = x_bf;  // reuse: x_bf dead after GEMM1

  (void)hipMemsetAsync(KVT, 0, SZ_KVT + 128 * 64 * 4, stream);

  cvt_bf16<<<16384, 256, 0, stream>>>(x, x_bf);
  cvt_bf16<<<384, 256, 0, stream>>>(wq, wq_bf);
  cvt_bf16<<<128, 256, 0, stream>>>(wp, wp_bf);

  gemm_bt<1><<<512 * 12, 256, 0, stream>>>(x_bf, wq_bf, qkv_bf, nullptr, ksumb,
                                           M_TOT, QKVN, C_, 12);
  kv_mfma<<<1024, 256, 0, stream>>>(qkv_bf, KVT);
  attn_out<<<8192, 256, 0, stream>>>(qkv_bf, KVT, ksumb, hout);
  gemm_bt<2><<<512 * 4, 256, 0, stream>>>(hout, wp_bf, out, bp, nullptr,
                                          M_TOT, C_, C_, 4);
}

// Round 7
// 370.254 us; speedup vs baseline: 1.7557x; 1.7557x over previous
//
#include <hip/hip_runtime.h>
#include <stdint.h>
#include <stddef.h>

// Problem constants
#define B_    16
#define N_SEQ 4096
#define C_    512
#define H_    8
#define E_    64
#define M_TOT (B_ * N_SEQ)   // 65536
#define QKVN  (3 * C_)       // 1536

typedef __attribute__((ext_vector_type(8))) short short8;
typedef __attribute__((ext_vector_type(4))) short s16x4;
typedef __attribute__((ext_vector_type(4))) float f32x4;

__device__ __forceinline__ unsigned short f2bf(float f) {
  uint32_t u = __builtin_bit_cast(uint32_t, f);
  return (unsigned short)((u + 0x7fffu + ((u >> 16) & 1u)) >> 16);  // RNE
}
__device__ __forceinline__ float bf2f(unsigned short h) {
  uint32_t u = ((uint32_t)h) << 16;
  return __builtin_bit_cast(float, u);
}

// ---------------------------------------------------------------- convert
__global__ __launch_bounds__(256) void cvt_bf16(const float* __restrict__ in,
                                                unsigned short* __restrict__ out) {
  size_t i = ((size_t)blockIdx.x * 256 + threadIdx.x) * 8;
  float4 a = *(const float4*)(in + i);
  float4 b = *(const float4*)(in + i + 4);
  short8 o;
  o[0] = (short)f2bf(a.x); o[1] = (short)f2bf(a.y);
  o[2] = (short)f2bf(a.z); o[3] = (short)f2bf(a.w);
  o[4] = (short)f2bf(b.x); o[5] = (short)f2bf(b.y);
  o[6] = (short)f2bf(b.z); o[7] = (short)f2bf(b.w);
  *(short8*)(out + i) = o;
}

#define GLD16(g, l)                                                              \
  __builtin_amdgcn_global_load_lds(                                              \
      (const __attribute__((address_space(1))) void*)(g),                        \
      (__attribute__((address_space(3))) void*)(l), 16, 0, 0)

// ---------------------------------------------------------------- GEMM (C = A * B^T), bf16 in, f32 accum
// 256x256 tile, BK=32, 8 waves (2M x 4N), ring-4 LDS double... quad-buffer,
// counted vmcnt pipeline (T3+T4): stage depth 3 tiles; per K-tile ONE barrier
// and s_waitcnt vmcnt(8) (never 0 in the main loop - loads stay in flight
// across barriers). Correctness: per-wave vmcnt(8) completes that wave's
// tile-kt loads; the following s_barrier makes it collective. The ring slot
// (kt+3)&3 staged this iteration was last READ in iteration kt-1, whose
// readers all passed this iteration's barrier.
// K fixed at 512 (16 K-tiles).
// MODE 1: qkv epilogue -> bf16 store, relu+0.125 on cols < 1024; ksum for k cols
// MODE 2: f32 store + bias
template <int MODE>
__global__ __launch_bounds__(512, 2) void gemm_bt(
    const unsigned short* __restrict__ A, const unsigned short* __restrict__ Bm,
    void* __restrict__ Cout, const float* __restrict__ bias,
    float* __restrict__ ksum, int M, int N, int NT) {
  const int K = 512;
  __shared__ unsigned short lds[4][2][8192];  // [ring buf][A|B][256 rows * 32 k]
  // XCD-aware bijective swizzle (grid % 8 == 0)
  const int q8 = gridDim.x >> 3;
  int bid = blockIdx.x;
  bid = (bid & 7) * q8 + (bid >> 3);
  const int mt = bid / NT, nt = bid - mt * NT;
  const int row0 = mt << 8, col0 = nt << 8;
  const int tid = threadIdx.x;
  const int lane = tid & 63, wave = tid >> 6;
  const int wm = wave & 1, wn = wave >> 1;  // wave tile: rows wm*128, cols wn*64
  const int fr = lane & 15, fg = lane >> 4;

  // staging: thread t covers (row = t>>2, 16B seg = t&3) and (+128 rows) for each of A,B
  const int r_t = tid >> 2, s_t = tid & 3;
  const unsigned short* gA0 = A + (size_t)(row0 + r_t) * K + s_t * 8;
  const unsigned short* gA1 = gA0 + (size_t)128 * K;
  const unsigned short* gB0 = Bm + (size_t)(col0 + r_t) * K + s_t * 8;
  const unsigned short* gB1 = gB0 + (size_t)128 * K;

  f32x4 acc[8][4] = {};

#define STAGE(kt)                                                    \
  {                                                                  \
    unsigned short* dA = &lds[(kt) & 3][0][tid * 8];                 \
    unsigned short* dB = &lds[(kt) & 3][1][tid * 8];                 \
    GLD16(gA0 + (kt) * 32, dA);                                      \
    GLD16(gA1 + (kt) * 32, dA + 4096);                               \
    GLD16(gB0 + (kt) * 32, dB);                                      \
    GLD16(gB1 + (kt) * 32, dB + 4096);                               \
  }

#define COMPUTE(kt, STG)                                             \
  {                                                                  \
    __builtin_amdgcn_s_barrier();                                    \
    __builtin_amdgcn_sched_barrier(0);                               \
    const unsigned short* cA = &lds[(kt) & 3][0][0];                 \
    const unsigned short* cB = &lds[(kt) & 3][1][0];                 \
    short8 af[8], bg[4];                                             \
    _Pragma("unroll")                                                \
    for (int m = 0; m < 8; m++)                                      \
      af[m] = *(const short8*)&cA[(wm * 128 + m * 16 + fr) * 32 + fg * 8]; \
    _Pragma("unroll")                                                \
    for (int n = 0; n < 4; n++)                                      \
      bg[n] = *(const short8*)&cB[(wn * 64 + n * 16 + fr) * 32 + fg * 8];  \
    if (STG) STAGE((kt) + 3);                                        \
    __builtin_amdgcn_sched_barrier(0);                               \
    _Pragma("unroll")                                                \
    for (int m = 0; m < 8; m++)                                      \
      _Pragma("unroll")                                              \
      for (int n = 0; n < 4; n++)                                    \
        acc[m][n] = __builtin_amdgcn_mfma_f32_16x16x32_bf16(af[m], bg[n], acc[m][n], 0, 0, 0); \
  }

  STAGE(0); STAGE(1); STAGE(2);   // 12 loads in flight

  for (int kt = 0; kt < 13; ++kt) {
    asm volatile("s_waitcnt vmcnt(8)" ::: "memory");   // tile kt landed; kt+1,kt+2 in flight
    COMPUTE(kt, 1);
  }
  asm volatile("s_waitcnt vmcnt(8)" ::: "memory");
  COMPUTE(13, 0);
  asm volatile("s_waitcnt vmcnt(4)" ::: "memory");
  COMPUTE(14, 0);
  asm volatile("s_waitcnt vmcnt(0)" ::: "memory");
  COMPUTE(15, 0);
#undef COMPUTE
#undef STAGE

  if (MODE == 1) {
    unsigned short* Cq = (unsigned short*)Cout;
    const bool isqk = (col0 < 2 * C_);
    const bool isk = (col0 >= C_) && (col0 < 2 * C_);
    float ksp[4] = {0.f, 0.f, 0.f, 0.f};
#pragma unroll
    for (int m = 0; m < 8; m++) {
      const int r0 = row0 + wm * 128 + m * 16 + fg * 4;
#pragma unroll
      for (int n = 0; n < 4; n++) {
        const int c = col0 + wn * 64 + n * 16 + fr;
#pragma unroll
        for (int r = 0; r < 4; r++) {
          float v = acc[m][n][r];
          if (isqk) v = fmaxf(v, 0.0f) + 0.125f;   // relu + E^-0.5
          if (isk) ksp[n] += v;
          Cq[(size_t)(r0 + r) * N + c] = f2bf(v);
        }
      }
    }
    if (isk) {
      const int b = row0 >> 12;
#pragma unroll
      for (int n = 0; n < 4; n++) {
        float s = ksp[n];
        s += __shfl_xor(s, 16, 64);
        s += __shfl_xor(s, 32, 64);
        if (lane < 16) {
          const int cc = col0 + wn * 64 + n * 16 + lane - C_;  // 0..511
          atomicAdd(&ksum[(size_t)((b << 3) + (cc >> 6)) * 64 + (cc & 63)], s);
        }
      }
    }
  } else {
    float* Cf = (float*)Cout;
#pragma unroll
    for (int m = 0; m < 8; m++) {
      const int r0 = row0 + wm * 128 + m * 16 + fg * 4;
#pragma unroll
      for (int n = 0; n < 4; n++) {
        const int c = col0 + wn * 64 + n * 16 + fr;
        const float bb = bias[c];
#pragma unroll
        for (int r = 0; r < 4; r++)
          Cf[(size_t)(r0 + r) * N + c] = acc[m][n][r] + bb;
      }
    }
  }
}

// ---------------------------------------------------------------- KV^T via MFMA
// KVT[bh][f][e] += sum_{n in chunk} v[n][f] * k_[n][e]
// grid: 128 bh * 8 chunks; block 256 (4 waves); wave w owns f-rows [16w,16w+16)
__global__ __launch_bounds__(256) void kv_mfma(const unsigned short* __restrict__ qkv,
                                               float* __restrict__ KVT) {
  const int bid = blockIdx.x;
  const int ch = bid & 7, bh = bid >> 3;
  const int h = bh & 7, b = bh >> 3;
  const int n0 = ch << 9;  // 512-row chunk
  __shared__ unsigned short ktile[64][68];
  __shared__ unsigned short vtile[64][68];
  const int tid = threadIdx.x;
  const int lane = tid & 63, w = tid >> 6;
  const int fr = lane & 15, fg = lane >> 4;
  const int srow = tid >> 3;            // 0..31
  const int sseg = (tid & 7) << 3;      // 0..56 step 8
  const unsigned short* gk = qkv + (size_t)(b * N_SEQ + n0 + srow) * QKVN + C_ + h * E_ + sseg;
  const unsigned short* gv = gk + C_;   // v is +512 elems within the row

  f32x4 acc[4] = {};
  short8 pk0, pk1, pv0, pv1;
  pk0 = *(const short8*)gk;
  pk1 = *(const short8*)(gk + (size_t)32 * QKVN);
  pv0 = *(const short8*)gv;
  pv1 = *(const short8*)(gv + (size_t)32 * QKVN);

  for (int it = 0; it < 8; ++it) {
    {
      s16x4* dk0 = (s16x4*)&ktile[srow][sseg];
      s16x4* dk1 = (s16x4*)&ktile[srow + 32][sseg];
      s16x4* dv0 = (s16x4*)&vtile[srow][sseg];
      s16x4* dv1 = (s16x4*)&vtile[srow + 32][sseg];
      const s16x4* s;
      s = (const s16x4*)&pk0; dk0[0] = s[0]; dk0[1] = s[1];
      s = (const s16x4*)&pk1; dk1[0] = s[0]; dk1[1] = s[1];
      s = (const s16x4*)&pv0; dv0[0] = s[0]; dv0[1] = s[1];
      s = (const s16x4*)&pv1; dv1[0] = s[0]; dv1[1] = s[1];
    }
    __syncthreads();
    if (it < 7) {
      const unsigned short* nk = gk + (size_t)(it + 1) * 64 * QKVN;
      const unsigned short* nv = gv + (size_t)(it + 1) * 64 * QKVN;
      pk0 = *(const short8*)nk;
      pk1 = *(const short8*)(nk + (size_t)32 * QKVN);
      pv0 = *(const short8*)nv;
      pv1 = *(const short8*)(nv + (size_t)32 * QKVN);
    }
#pragma unroll
    for (int ks = 0; ks < 2; ++ks) {
      const int kb = ks * 32;
      short8 av, bk0, bk1, bk2, bk3;
#pragma unroll
      for (int j = 0; j < 8; ++j) {
        const int row = kb + fg * 8 + j;
        av[j]  = (short)vtile[row][w * 16 + fr];
        bk0[j] = (short)ktile[row][fr];
        bk1[j] = (short)ktile[row][16 + fr];
        bk2[j] = (short)ktile[row][32 + fr];
        bk3[j] = (short)ktile[row][48 + fr];
      }
      acc[0] = __builtin_amdgcn_mfma_f32_16x16x32_bf16(av, bk0, acc[0], 0, 0, 0);
      acc[1] = __builtin_amdgcn_mfma_f32_16x16x32_bf16(av, bk1, acc[1], 0, 0, 0);
      acc[2] = __builtin_amdgcn_mfma_f32_16x16x32_bf16(av, bk2, acc[2], 0, 0, 0);
      acc[3] = __builtin_amdgcn_mfma_f32_16x16x32_bf16(av, bk3, acc[3], 0, 0, 0);
    }
    __syncthreads();
  }

  const size_t fbase = (size_t)bh * 64 + w * 16 + fg * 4;
#pragma unroll
  for (int e = 0; e < 4; ++e)
#pragma unroll
    for (int r = 0; r < 4; ++r)
      atomicAdd(&KVT[(fbase + r) * 64 + e * 16 + fr], acc[e][r]);
}

// ---------------------------------------------------------------- attention output
__global__ __launch_bounds__(256) void attn_out(const unsigned short* __restrict__ qkv,
                                                const float* __restrict__ KVT,
                                                const float* __restrict__ ksum,
                                                unsigned short* __restrict__ hout) {
  const int bid = blockIdx.x;
  const int nc = bid & 63, bh = bid >> 6;
  const int h = bh & 7, b = bh >> 3;
  const int n0 = nc << 6;  // 64-row chunk
  __shared__ float qs[64][68];
  __shared__ float denp[64][4];
  __shared__ float zl[64];
  __shared__ float kss[64];
  const int t = threadIdx.x;

#pragma unroll
  for (int half = 0; half < 2; half++) {
    const int row = (t >> 3) + half * 32;
    const int e0 = (t & 7) * 8;
    const unsigned short* srcq = qkv + (size_t)(b * N_SEQ + n0 + row) * QKVN + h * E_ + e0;
    short8 raw = *(const short8*)srcq;
#pragma unroll
    for (int i = 0; i < 8; i++) qs[row][e0 + i] = bf2f((unsigned short)raw[i]);
  }
  if (t < 64) kss[t] = ksum[bh * 64 + t];
  __syncthreads();

  {
    const int r = t >> 2, qp = t & 3;
    float s = 0.f;
#pragma unroll
    for (int e = 0; e < 16; e++) s = fmaf(qs[r][qp * 16 + e], kss[qp * 16 + e], s);
    denp[r][qp] = s;
  }
  __syncthreads();
  if (t < 64) zl[t] = 1.0f / (denp[t][0] + denp[t][1] + denp[t][2] + denp[t][3] + 1e-6f);
  __syncthreads();

  const int f = t & 63, rg = t >> 6;
  float kvc[64];
  const float* kvp = KVT + (size_t)bh * 4096 + (size_t)f * 64;
#pragma unroll
  for (int i = 0; i < 16; i++) {
    float4 v4 = *(const float4*)(kvp + i * 4);
    kvc[4 * i] = v4.x; kvc[4 * i + 1] = v4.y; kvc[4 * i + 2] = v4.z; kvc[4 * i + 3] = v4.w;
  }
#pragma unroll
  for (int i = 0; i < 16; i++) {
    const int row = rg * 16 + i;
    float a = 0.f;
#pragma unroll
    for (int e4 = 0; e4 < 16; e4++) {
      float4 qv = *(const float4*)&qs[row][e4 * 4];
      a = fmaf(qv.x, kvc[4 * e4 + 0], a);
      a = fmaf(qv.y, kvc[4 * e4 + 1], a);
      a = fmaf(qv.z, kvc[4 * e4 + 2], a);
      a = fmaf(qv.w, kvc[4 * e4 + 3], a);
    }
    const float val = a * zl[row];
    hout[(size_t)(b * N_SEQ + n0 + row) * C_ + h * E_ + f] = f2bf(val);
  }
}

// ---------------------------------------------------------------- launcher
extern "C" void kernel_launch(void* const* d_in, const int* in_sizes, int n_in,
                              void* d_out, int out_size, void* d_ws, size_t ws_size,
                              hipStream_t stream) {
  const float* x  = (const float*)d_in[0];
  const float* wq = (const float*)d_in[1];
  const float* wp = (const float*)d_in[2];
  const float* bp = (const float*)d_in[3];
  float* out = (float*)d_out;

  char* ws = (char*)d_ws;
  const size_t SZ_XBF  = (size_t)M_TOT * C_ * 2;      //  67108864
  const size_t SZ_QKV  = (size_t)M_TOT * QKVN * 2;    // 201326592
  const size_t SZ_WQ   = (size_t)QKVN * C_ * 2;       //   1572864
  const size_t SZ_WP   = (size_t)C_ * C_ * 2;         //    524288
  const size_t SZ_KVT  = (size_t)128 * 64 * 64 * 4;   //   2097152
  unsigned short* x_bf   = (unsigned short*)(ws);
  unsigned short* qkv_bf = (unsigned short*)(ws + SZ_XBF);
  unsigned short* wq_bf  = (unsigned short*)(ws + SZ_XBF + SZ_QKV);
  unsigned short* wp_bf  = (unsigned short*)(ws + SZ_XBF + SZ_QKV + SZ_WQ);
  float* KVT   = (float*)(ws + SZ_XBF + SZ_QKV + SZ_WQ + SZ_WP);
  float* ksumb = (float*)(ws + SZ_XBF + SZ_QKV + SZ_WQ + SZ_WP + SZ_KVT);
  unsigned short* hout = x_bf;  // reuse: x_bf dead after GEMM1

  (void)hipMemsetAsync(KVT, 0, SZ_KVT + 128 * 64 * 4, stream);

  cvt_bf16<<<16384, 256, 0, stream>>>(x, x_bf);
  cvt_bf16<<<384, 256, 0, stream>>>(wq, wq_bf);
  cvt_bf16<<<128, 256, 0, stream>>>(wp, wp_bf);

  gemm_bt<1><<<256 * 6, 512, 0, stream>>>(x_bf, wq_bf, qkv_bf, nullptr, ksumb,
                                          M_TOT, QKVN, 6);
  kv_mfma<<<1024, 256, 0, stream>>>(qkv_bf, KVT);
  attn_out<<<8192, 256, 0, stream>>>(qkv_bf, KVT, ksumb, hout);
  gemm_bt<2><<<256 * 2, 512, 0, stream>>>(hout, wp_bf, out, bp, nullptr,
                                          M_TOT, C_, 2);
}

// Round 8
// 354.943 us; speedup vs baseline: 1.8314x; 1.0431x over previous
//
#include <hip/hip_runtime.h>
#include <stdint.h>
#include <stddef.h>

// Problem constants
#define B_    16
#define N_SEQ 4096
#define C_    512
#define H_    8
#define E_    64
#define M_TOT (B_ * N_SEQ)   // 65536
#define QKVN  (3 * C_)       // 1536

typedef __attribute__((ext_vector_type(8))) short short8;
typedef __attribute__((ext_vector_type(4))) short s16x4;
typedef __attribute__((ext_vector_type(4))) float f32x4;

__device__ __forceinline__ unsigned short f2bf(float f) {
  uint32_t u = __builtin_bit_cast(uint32_t, f);
  return (unsigned short)((u + 0x7fffu + ((u >> 16) & 1u)) >> 16);  // RNE
}
__device__ __forceinline__ float bf2f(unsigned short h) {
  uint32_t u = ((uint32_t)h) << 16;
  return __builtin_bit_cast(float, u);
}

// ---------------------------------------------------------------- convert
__global__ __launch_bounds__(256) void cvt_bf16(const float* __restrict__ in,
                                                unsigned short* __restrict__ out) {
  size_t i = ((size_t)blockIdx.x * 256 + threadIdx.x) * 8;
  float4 a = *(const float4*)(in + i);
  float4 b = *(const float4*)(in + i + 4);
  short8 o;
  o[0] = (short)f2bf(a.x); o[1] = (short)f2bf(a.y);
  o[2] = (short)f2bf(a.z); o[3] = (short)f2bf(a.w);
  o[4] = (short)f2bf(b.x); o[5] = (short)f2bf(b.y);
  o[6] = (short)f2bf(b.z); o[7] = (short)f2bf(b.w);
  *(short8*)(out + i) = o;
}

#define GLD16(g, l)                                                              \
  __builtin_amdgcn_global_load_lds(                                              \
      (const __attribute__((address_space(1))) void*)(g),                        \
      (__attribute__((address_space(3))) void*)(l), 16, 0, 0)

// ---------------------------------------------------------------- GEMM (C = A * B^T), bf16 in, f32 accum
// 256x256 tile, BK=64, 8 waves (2M x 4N, wave-tile 128x64), double-buffered LDS.
// T2 swizzle: LDS position (row, slot') holds global 16B slot = slot' ^ (row&7).
//  - write: thread stages global (row = q>>3, slot = (q&7)^((q>>3)&7)) into linear
//    LDS position q (global_load_lds dest = q*16B). The 8 lanes covering one row
//    read its full 128B line in permuted order -> coalescing preserved.
//  - read: fragment (row, k-slot 4kk+fg) fetched at slot' = (4kk+fg)^(fr&7):
//    every 8 consecutive lanes hit 8 distinct bank-quads -> conflict-free b128.
// Schedule per K-tile (minimum 2-phase, verified-safe):
//   STAGE(kt+1) -> ds_read frags(kt) -> setprio(1) 64 MFMA setprio(0) -> __syncthreads()
// (syncthreads drains vmcnt; stage latency hidden under the MFMA phase)
// MODE 1: qkv epilogue -> bf16 store, relu+0.125 on cols < 1024; ksum for k cols
// MODE 2: f32 store + bias
template <int MODE>
__global__ __launch_bounds__(512, 2) void gemm_bt(
    const unsigned short* __restrict__ A, const unsigned short* __restrict__ Bm,
    void* __restrict__ Cout, const float* __restrict__ bias,
    float* __restrict__ ksum, int M, int N, int NT) {
  const int K = 512;
  __shared__ unsigned short lds[2][2][256 * 64];  // [dbuf][A|B][256 rows x 64 k] = 128 KiB
  // XCD-aware bijective swizzle (grid % 8 == 0)
  const int q8 = gridDim.x >> 3;
  int bid = blockIdx.x;
  bid = (bid & 7) * q8 + (bid >> 3);
  const int mt = bid / NT, nt = bid - mt * NT;
  const int row0 = mt << 8, col0 = nt << 8;
  const int tid = threadIdx.x;
  const int lane = tid & 63, wave = tid >> 6;
  const int wm = wave & 1, wn = wave >> 1;  // wave tile: rows wm*128, cols wn*64
  const int fr = lane & 15, fg = lane >> 4;

  // staging geometry: per matrix per K-tile, 4 issues; issue i, thread t covers
  // LDS position q = i*512 + t  (row = q>>3, slot' = q&7)
  const int s_row = tid >> 3;                          // 0..63 (+64 per issue)
  const int s_slot = (tid & 7) ^ (s_row & 7);          // pre-swizzled global slot
  const unsigned short* gA = A + (size_t)(row0 + s_row) * K + s_slot * 8;
  const unsigned short* gB = Bm + (size_t)(col0 + s_row) * K + s_slot * 8;

  f32x4 acc[8][4] = {};

#define STAGE(kt)                                                        \
  {                                                                      \
    unsigned short* dA = &lds[(kt) & 1][0][tid * 8];                     \
    unsigned short* dB = &lds[(kt) & 1][1][tid * 8];                     \
    _Pragma("unroll")                                                    \
    for (int i = 0; i < 4; i++) {                                        \
      GLD16(gA + (size_t)i * 64 * K + (kt) * 64, dA + i * 4096);         \
      GLD16(gB + (size_t)i * 64 * K + (kt) * 64, dB + i * 4096);         \
    }                                                                    \
  }

  STAGE(0);
  __syncthreads();

  for (int kt = 0; kt < 8; ++kt) {
    if (kt < 7) STAGE(kt + 1);
    const unsigned short* bufA = &lds[kt & 1][0][0];
    const unsigned short* bufB = &lds[kt & 1][1][0];
#pragma unroll
    for (int kk = 0; kk < 2; ++kk) {
      const int sl = ((kk * 4 + fg) ^ (fr & 7)) * 8;   // swizzled 16B slot (elems)
      short8 af[8], bg[4];
#pragma unroll
      for (int m = 0; m < 8; m++)
        af[m] = *(const short8*)&bufA[(wm * 128 + m * 16 + fr) * 64 + sl];
#pragma unroll
      for (int n = 0; n < 4; n++)
        bg[n] = *(const short8*)&bufB[(wn * 64 + n * 16 + fr) * 64 + sl];
      __builtin_amdgcn_s_setprio(1);
#pragma unroll
      for (int m = 0; m < 8; m++)
#pragma unroll
        for (int n = 0; n < 4; n++)
          acc[m][n] = __builtin_amdgcn_mfma_f32_16x16x32_bf16(af[m], bg[n], acc[m][n], 0, 0, 0);
      __builtin_amdgcn_s_setprio(0);
    }
    __syncthreads();   // drains vmcnt -> stage(kt+1) landed; joins readers of buf kt&1
  }
#undef STAGE

  if (MODE == 1) {
    unsigned short* Cq = (unsigned short*)Cout;
    const bool isqk = (col0 < 2 * C_);
    const bool isk = (col0 >= C_) && (col0 < 2 * C_);
    float ksp[4] = {0.f, 0.f, 0.f, 0.f};
#pragma unroll
    for (int m = 0; m < 8; m++) {
      const int r0 = row0 + wm * 128 + m * 16 + fg * 4;
#pragma unroll
      for (int n = 0; n < 4; n++) {
        const int c = col0 + wn * 64 + n * 16 + fr;
#pragma unroll
        for (int r = 0; r < 4; r++) {
          float v = acc[m][n][r];
          if (isqk) v = fmaxf(v, 0.0f) + 0.125f;   // relu + E^-0.5
          if (isk) ksp[n] += v;
          Cq[(size_t)(r0 + r) * N + c] = f2bf(v);
        }
      }
    }
    if (isk) {
      const int b = row0 >> 12;
#pragma unroll
      for (int n = 0; n < 4; n++) {
        float s = ksp[n];
        s += __shfl_xor(s, 16, 64);
        s += __shfl_xor(s, 32, 64);
        if (lane < 16) {
          const int cc = col0 + wn * 64 + n * 16 + lane - C_;  // 0..511
          atomicAdd(&ksum[(size_t)((b << 3) + (cc >> 6)) * 64 + (cc & 63)], s);
        }
      }
    }
  } else {
    float* Cf = (float*)Cout;
#pragma unroll
    for (int m = 0; m < 8; m++) {
      const int r0 = row0 + wm * 128 + m * 16 + fg * 4;
#pragma unroll
      for (int n = 0; n < 4; n++) {
        const int c = col0 + wn * 64 + n * 16 + fr;
        const float bb = bias[c];
#pragma unroll
        for (int r = 0; r < 4; r++)
          Cf[(size_t)(r0 + r) * N + c] = acc[m][n][r] + bb;
      }
    }
  }
}

// ---------------------------------------------------------------- KV^T via MFMA
// KVT[bh][f][e] += sum_{n in chunk} v[n][f] * k_[n][e]
// grid: 128 bh * 8 chunks; block 256 (4 waves); wave w owns f-rows [16w,16w+16)
__global__ __launch_bounds__(256) void kv_mfma(const unsigned short* __restrict__ qkv,
                                               float* __restrict__ KVT) {
  const int bid = blockIdx.x;
  const int ch = bid & 7, bh = bid >> 3;
  const int h = bh & 7, b = bh >> 3;
  const int n0 = ch << 9;  // 512-row chunk
  __shared__ unsigned short ktile[64][68];
  __shared__ unsigned short vtile[64][68];
  const int tid = threadIdx.x;
  const int lane = tid & 63, w = tid >> 6;
  const int fr = lane & 15, fg = lane >> 4;
  const int srow = tid >> 3;            // 0..31
  const int sseg = (tid & 7) << 3;      // 0..56 step 8
  const unsigned short* gk = qkv + (size_t)(b * N_SEQ + n0 + srow) * QKVN + C_ + h * E_ + sseg;
  const unsigned short* gv = gk + C_;   // v is +512 elems within the row

  f32x4 acc[4] = {};
  short8 pk0, pk1, pv0, pv1;
  pk0 = *(const short8*)gk;
  pk1 = *(const short8*)(gk + (size_t)32 * QKVN);
  pv0 = *(const short8*)gv;
  pv1 = *(const short8*)(gv + (size_t)32 * QKVN);

  for (int it = 0; it < 8; ++it) {
    {
      s16x4* dk0 = (s16x4*)&ktile[srow][sseg];
      s16x4* dk1 = (s16x4*)&ktile[srow + 32][sseg];
      s16x4* dv0 = (s16x4*)&vtile[srow][sseg];
      s16x4* dv1 = (s16x4*)&vtile[srow + 32][sseg];
      const s16x4* s;
      s = (const s16x4*)&pk0; dk0[0] = s[0]; dk0[1] = s[1];
      s = (const s16x4*)&pk1; dk1[0] = s[0]; dk1[1] = s[1];
      s = (const s16x4*)&pv0; dv0[0] = s[0]; dv0[1] = s[1];
      s = (const s16x4*)&pv1; dv1[0] = s[0]; dv1[1] = s[1];
    }
    __syncthreads();
    if (it < 7) {
      const unsigned short* nk = gk + (size_t)(it + 1) * 64 * QKVN;
      const unsigned short* nv = gv + (size_t)(it + 1) * 64 * QKVN;
      pk0 = *(const short8*)nk;
      pk1 = *(const short8*)(nk + (size_t)32 * QKVN);
      pv0 = *(const short8*)nv;
      pv1 = *(const short8*)(nv + (size_t)32 * QKVN);
    }
#pragma unroll
    for (int ks = 0; ks < 2; ++ks) {
      const int kb = ks * 32;
      short8 av, bk0, bk1, bk2, bk3;
#pragma unroll
      for (int j = 0; j < 8; ++j) {
        const int row = kb + fg * 8 + j;
        av[j]  = (short)vtile[row][w * 16 + fr];
        bk0[j] = (short)ktile[row][fr];
        bk1[j] = (short)ktile[row][16 + fr];
        bk2[j] = (short)ktile[row][32 + fr];
        bk3[j] = (short)ktile[row][48 + fr];
      }
      acc[0] = __builtin_amdgcn_mfma_f32_16x16x32_bf16(av, bk0, acc[0], 0, 0, 0);
      acc[1] = __builtin_amdgcn_mfma_f32_16x16x32_bf16(av, bk1, acc[1], 0, 0, 0);
      acc[2] = __builtin_amdgcn_mfma_f32_16x16x32_bf16(av, bk2, acc[2], 0, 0, 0);
      acc[3] = __builtin_amdgcn_mfma_f32_16x16x32_bf16(av, bk3, acc[3], 0, 0, 0);
    }
    __syncthreads();
  }

  const size_t fbase = (size_t)bh * 64 + w * 16 + fg * 4;
#pragma unroll
  for (int e = 0; e < 4; ++e)
#pragma unroll
    for (int r = 0; r < 4; ++r)
      atomicAdd(&KVT[(fbase + r) * 64 + e * 16 + fr], acc[e][r]);
}

// ---------------------------------------------------------------- attention output
__global__ __launch_bounds__(256) void attn_out(const unsigned short* __restrict__ qkv,
                                                const float* __restrict__ KVT,
                                                const float* __restrict__ ksum,
                                                unsigned short* __restrict__ hout) {
  const int bid = blockIdx.x;
  const int nc = bid & 63, bh = bid >> 6;
  const int h = bh & 7, b = bh >> 3;
  const int n0 = nc << 6;  // 64-row chunk
  __shared__ float qs[64][68];
  __shared__ float denp[64][4];
  __shared__ float zl[64];
  __shared__ float kss[64];
  const int t = threadIdx.x;

#pragma unroll
  for (int half = 0; half < 2; half++) {
    const int row = (t >> 3) + half * 32;
    const int e0 = (t & 7) * 8;
    const unsigned short* srcq = qkv + (size_t)(b * N_SEQ + n0 + row) * QKVN + h * E_ + e0;
    short8 raw = *(const short8*)srcq;
#pragma unroll
    for (int i = 0; i < 8; i++) qs[row][e0 + i] = bf2f((unsigned short)raw[i]);
  }
  if (t < 64) kss[t] = ksum[bh * 64 + t];
  __syncthreads();

  {
    const int r = t >> 2, qp = t & 3;
    float s = 0.f;
#pragma unroll
    for (int e = 0; e < 16; e++) s = fmaf(qs[r][qp * 16 + e], kss[qp * 16 + e], s);
    denp[r][qp] = s;
  }
  __syncthreads();
  if (t < 64) zl[t] = 1.0f / (denp[t][0] + denp[t][1] + denp[t][2] + denp[t][3] + 1e-6f);
  __syncthreads();

  const int f = t & 63, rg = t >> 6;
  float kvc[64];
  const float* kvp = KVT + (size_t)bh * 4096 + (size_t)f * 64;
#pragma unroll
  for (int i = 0; i < 16; i++) {
    float4 v4 = *(const float4*)(kvp + i * 4);
    kvc[4 * i] = v4.x; kvc[4 * i + 1] = v4.y; kvc[4 * i + 2] = v4.z; kvc[4 * i + 3] = v4.w;
  }
#pragma unroll
  for (int i = 0; i < 16; i++) {
    const int row = rg * 16 + i;
    float a = 0.f;
#pragma unroll
    for (int e4 = 0; e4 < 16; e4++) {
      float4 qv = *(const float4*)&qs[row][e4 * 4];
      a = fmaf(qv.x, kvc[4 * e4 + 0], a);
      a = fmaf(qv.y, kvc[4 * e4 + 1], a);
      a = fmaf(qv.z, kvc[4 * e4 + 2], a);
      a = fmaf(qv.w, kvc[4 * e4 + 3], a);
    }
    const float val = a * zl[row];
    hout[(size_t)(b * N_SEQ + n0 + row) * C_ + h * E_ + f] = f2bf(val);
  }
}

// ---------------------------------------------------------------- launcher
extern "C" void kernel_launch(void* const* d_in, const int* in_sizes, int n_in,
                              void* d_out, int out_size, void* d_ws, size_t ws_size,
                              hipStream_t stream) {
  const float* x  = (const float*)d_in[0];
  const float* wq = (const float*)d_in[1];
  const float* wp = (const float*)d_in[2];
  const float* bp = (const float*)d_in[3];
  float* out = (float*)d_out;

  char* ws = (char*)d_ws;
  const size_t SZ_XBF  = (size_t)M_TOT * C_ * 2;      //  67108864
  const size_t SZ_QKV  = (size_t)M_TOT * QKVN * 2;    // 201326592
  const size_t SZ_WQ   = (size_t)QKVN * C_ * 2;       //   1572864
  const size_t SZ_WP   = (size_t)C_ * C_ * 2;         //    524288
  const size_t SZ_KVT  = (size_t)128 * 64 * 64 * 4;   //   2097152
  unsigned short* x_bf   = (unsigned short*)(ws);
  unsigned short* qkv_bf = (unsigned short*)(ws + SZ_XBF);
  unsigned short* wq_bf  = (unsigned short*)(ws + SZ_XBF + SZ_QKV);
  unsigned short* wp_bf  = (unsigned short*)(ws + SZ_XBF + SZ_QKV + SZ_WQ);
  float* KVT   = (float*)(ws + SZ_XBF + SZ_QKV + SZ_WQ + SZ_WP);
  float* ksumb = (float*)(ws + SZ_XBF + SZ_QKV + SZ_WQ + SZ_WP + SZ_KVT);
  unsigned short* hout = x_bf;  // reuse: x_bf dead after GEMM1

  (void)hipMemsetAsync(KVT, 0, SZ_KVT + 128 * 64 * 4, stream);

  cvt_bf16<<<16384, 256, 0, stream>>>(x, x_bf);
  cvt_bf16<<<384, 256, 0, stream>>>(wq, wq_bf);
  cvt_bf16<<<128, 256, 0, stream>>>(wp, wp_bf);

  gemm_bt<1><<<1536, 512, 0, stream>>>(x_bf, wq_bf, qkv_bf, nullptr, ksumb,
                                       M_TOT, QKVN, 6);
  kv_mfma<<<1024, 256, 0, stream>>>(qkv_bf, KVT);
  attn_out<<<8192, 256, 0, stream>>>(qkv_bf, KVT, ksumb, hout);
  gemm_bt<2><<<512, 512, 0, stream>>>(hout, wp_bf, out, bp, nullptr,
                                      M_TOT, C_, 2);
}

// Round 9
// 350.647 us; speedup vs baseline: 1.8539x; 1.0123x over previous
//
#include <hip/hip_runtime.h>
#include <stdint.h>
#include <stddef.h>

// Problem constants
#define B_    16
#define N_SEQ 4096
#define C_    512
#define H_    8
#define E_    64
#define M_TOT (B_ * N_SEQ)   // 65536
#define QKVN  (3 * C_)       // 1536

typedef __attribute__((ext_vector_type(8))) short short8;
typedef __attribute__((ext_vector_type(4))) short s16x4;
typedef __attribute__((ext_vector_type(4))) float f32x4;

__device__ __forceinline__ unsigned short f2bf(float f) {
  uint32_t u = __builtin_bit_cast(uint32_t, f);
  return (unsigned short)((u + 0x7fffu + ((u >> 16) & 1u)) >> 16);  // RNE
}
__device__ __forceinline__ float bf2f(unsigned short h) {
  uint32_t u = ((uint32_t)h) << 16;
  return __builtin_bit_cast(float, u);
}

// ---------------------------------------------------------------- convert
__global__ __launch_bounds__(256) void cvt_bf16(const float* __restrict__ in,
                                                unsigned short* __restrict__ out) {
  size_t i = ((size_t)blockIdx.x * 256 + threadIdx.x) * 8;
  float4 a = *(const float4*)(in + i);
  float4 b = *(const float4*)(in + i + 4);
  short8 o;
  o[0] = (short)f2bf(a.x); o[1] = (short)f2bf(a.y);
  o[2] = (short)f2bf(a.z); o[3] = (short)f2bf(a.w);
  o[4] = (short)f2bf(b.x); o[5] = (short)f2bf(b.y);
  o[6] = (short)f2bf(b.z); o[7] = (short)f2bf(b.w);
  *(short8*)(out + i) = o;
}

#define GLD16(g, l)                                                              \
  __builtin_amdgcn_global_load_lds(                                              \
      (const __attribute__((address_space(1))) void*)(g),                        \
      (__attribute__((address_space(3))) void*)(l), 16, 0, 0)

// ---------------------------------------------------------------- GEMM (C = A * B^T), bf16 in, f32 accum
// 8-phase 256x256 schedule (m201-style port):
//  - BM=BN=256, BK=64, 8 waves (2M x 4N), wave tile 128x64.
//  - LDS sm[2 dbuf][A|B][2 half][128x64] = 128 KiB. Halves are CONSUMPTION-
//    aligned: A-half = tile rows with bit6 (0-63,128-191 | 64-127,192-255),
//    read only in phases with matching mg; B-half = bit5, matching ng2.
//  - Per K-tile t: 4 phases (mg,ng2) = (0,0),(1,0),(0,1),(1,1). Each phase:
//    {ds_read frags | stage one half-tile of t+1 | counted vmcnt | barrier |
//     lgkmcnt(0) | setprio(1) 16 MFMA setprio(0) | barrier}.
//  - Counted vmcnt, never 0 in main loop: entering tile t outstanding =
//    {A1(t),B1(t)}; p0 stages A0(t+1), vmcnt(4) => A1(t) ready; p1 stages
//    B0(t+1), vmcnt(4) => B1(t); p2 stages A1(t+1), no wait; p3 stages
//    B1(t+1), vmcnt(4) => A0,B0(t+1). Last tile drains 2 -> 0.
//  - T2 XOR slot swizzle (conflict-free, verified R8): LDS slot s' holds
//    global 16B slot s'^(row&7); read offset (kk*4+fg)^(fr&7).
// MODE 1: qkv epilogue -> bf16 store, relu+0.125 on cols < 1024; ksum for k cols
// MODE 2: f32 store + bias
template <int MODE>
__global__ __launch_bounds__(512, 2) void gemm_bt(
    const unsigned short* __restrict__ A, const unsigned short* __restrict__ Bm,
    void* __restrict__ Cout, const float* __restrict__ bias,
    float* __restrict__ ksum, int M, int N, int NT) {
  const int K = 512;
  __shared__ unsigned short sm[2][2][2][128 * 64];  // [buf][A|B][half][rows x k]
  // XCD-aware bijective swizzle (grid % 8 == 0)
  const int q8 = gridDim.x >> 3;
  int bid = blockIdx.x;
  bid = (bid & 7) * q8 + (bid >> 3);
  const int mt = bid / NT, nt = bid - mt * NT;
  const int row0 = mt << 8, col0 = nt << 8;
  const int tid = threadIdx.x;
  const int lane = tid & 63, wave = tid >> 6;
  const int wm = wave & 1, wn = wave >> 1;  // wave tile: rows wm*128, cols wn*64
  const int fr = lane & 15, fg = lane >> 4;
  const int swz0 = ((fg) ^ (fr & 7)) * 8;       // kk=0 swizzled slot (elems)
  const int swz1 = ((4 + fg) ^ (fr & 7)) * 8;   // kk=1

  // staging source addresses (pre-swizzled global slot)
  const int rsA = tid >> 3;                              // packed row 0..63 (round1: +128*K)
  const int ssw = ((tid & 7) ^ (rsA & 7)) * 8;           // swizzled 16B slot -> elems
  const int rsB = (rsA & 31) + ((rsA >> 5) << 6);        // B packed-row unpack
  const unsigned short* gA = A + (size_t)(row0 + rsA) * K + ssw;
  const unsigned short* gB = Bm + (size_t)(col0 + rsB) * K + ssw;

  f32x4 acc[8][4] = {};
  short8 aw[2][4][2];   // [mg][m][kk] resident A fragments
  short8 bw[2][2];      // [n][kk] current B pair

#define STAGE_A(buf, hA, kt)                                                   \
  {                                                                            \
    unsigned short* d = &sm[buf][0][hA][tid * 8];                              \
    GLD16(gA + (size_t)(hA) * 64 * K + (size_t)(kt) * 64, d);                  \
    GLD16(gA + (size_t)(hA) * 64 * K + (size_t)128 * K + (size_t)(kt) * 64,    \
          d + 4096);                                                           \
  }
#define STAGE_B(buf, hB, kt)                                                   \
  {                                                                            \
    unsigned short* d = &sm[buf][1][hB][tid * 8];                              \
    GLD16(gB + (size_t)(hB) * 32 * K + (size_t)(kt) * 64, d);                  \
    GLD16(gB + (size_t)(hB) * 32 * K + (size_t)128 * K + (size_t)(kt) * 64,    \
          d + 4096);                                                           \
  }
#define RDA(buf, mg)                                                           \
  _Pragma("unroll") for (int m = 0; m < 4; m++) {                              \
    const unsigned short* p = &sm[buf][0][mg][(wm * 64 + m * 16 + fr) * 64];   \
    aw[mg][m][0] = *(const short8*)(p + swz0);                                 \
    aw[mg][m][1] = *(const short8*)(p + swz1);                                 \
  }
#define RDB(buf, ng2)                                                          \
  _Pragma("unroll") for (int n = 0; n < 2; n++) {                              \
    const unsigned short* p = &sm[buf][1][ng2][(wn * 32 + n * 16 + fr) * 64];  \
    bw[n][0] = *(const short8*)(p + swz0);                                     \
    bw[n][1] = *(const short8*)(p + swz1);                                     \
  }
#define MFMA16(mg, ng2)                                                        \
  __builtin_amdgcn_s_setprio(1);                                               \
  _Pragma("unroll") for (int m = 0; m < 4; m++)                                \
  _Pragma("unroll") for (int n = 0; n < 2; n++)                                \
  _Pragma("unroll") for (int kk = 0; kk < 2; kk++)                             \
    acc[(mg)*4 + m][(ng2)*2 + n] = __builtin_amdgcn_mfma_f32_16x16x32_bf16(    \
        aw[mg][m][kk], bw[n][kk], acc[(mg)*4 + m][(ng2)*2 + n], 0, 0, 0);      \
  __builtin_amdgcn_s_setprio(0);
#define VMC(n) asm volatile("s_waitcnt vmcnt(" #n ")" ::: "memory")
#define LKC0() asm volatile("s_waitcnt lgkmcnt(0)" ::: "memory")
#define BARF()                                                                 \
  asm volatile("" ::: "memory");                                               \
  __builtin_amdgcn_s_barrier();                                                \
  asm volatile("" ::: "memory")

  // prologue: tile 0's halves in order A0,B0,A1,B1
  STAGE_A(0, 0, 0); STAGE_B(0, 0, 0); STAGE_A(0, 1, 0); STAGE_B(0, 1, 0);
  VMC(4);            // A0(0), B0(0) landed; {A1(0),B1(0)} in flight
  BARF();

  for (int t = 0; t < 7; ++t) {
    const int b = t & 1, nb = b ^ 1;
    // phase 0: (mg0, ng0)
    RDA(b, 0); RDB(b, 0);
    STAGE_A(nb, 0, t + 1);
    VMC(4);  BARF();  LKC0();  __builtin_amdgcn_sched_barrier(0);
    MFMA16(0, 0);
    BARF();
    // phase 1: (mg1, ng0)
    RDA(b, 1);
    STAGE_B(nb, 0, t + 1);
    VMC(4);  BARF();  LKC0();  __builtin_amdgcn_sched_barrier(0);
    MFMA16(1, 0);
    BARF();
    // phase 2: (mg0, ng1)
    RDB(b, 1);
    STAGE_A(nb, 1, t + 1);
    BARF();  LKC0();  __builtin_amdgcn_sched_barrier(0);
    MFMA16(0, 1);
    BARF();
    // phase 3: (mg1, ng1)
    STAGE_B(nb, 1, t + 1);
    VMC(4);  BARF();  LKC0();  __builtin_amdgcn_sched_barrier(0);
    MFMA16(1, 1);
    BARF();
  }
  // tile 7 (buf 1): no stages, drain 2 -> 0
  RDA(1, 0); RDB(1, 0);
  VMC(2);  BARF();  LKC0();  __builtin_amdgcn_sched_barrier(0);
  MFMA16(0, 0);
  BARF();
  RDA(1, 1);
  VMC(0);  BARF();  LKC0();  __builtin_amdgcn_sched_barrier(0);
  MFMA16(1, 0);
  BARF();
  RDB(1, 1);
  BARF();  LKC0();  __builtin_amdgcn_sched_barrier(0);
  MFMA16(0, 1);
  BARF();
  MFMA16(1, 1);

#undef STAGE_A
#undef STAGE_B
#undef RDA
#undef RDB
#undef MFMA16
#undef VMC
#undef LKC0
#undef BARF

  if (MODE == 1) {
    unsigned short* Cq = (unsigned short*)Cout;
    const bool isqk = (col0 < 2 * C_);
    const bool isk = (col0 >= C_) && (col0 < 2 * C_);
    float ksp[4] = {0.f, 0.f, 0.f, 0.f};
#pragma unroll
    for (int m = 0; m < 8; m++) {
      const int r0 = row0 + wm * 128 + m * 16 + fg * 4;
#pragma unroll
      for (int n = 0; n < 4; n++) {
        const int c = col0 + wn * 64 + n * 16 + fr;
#pragma unroll
        for (int r = 0; r < 4; r++) {
          float v = acc[m][n][r];
          if (isqk) v = fmaxf(v, 0.0f) + 0.125f;   // relu + E^-0.5
          if (isk) ksp[n] += v;
          Cq[(size_t)(r0 + r) * N + c] = f2bf(v);
        }
      }
    }
    if (isk) {
      const int b = row0 >> 12;
#pragma unroll
      for (int n = 0; n < 4; n++) {
        float s = ksp[n];
        s += __shfl_xor(s, 16, 64);
        s += __shfl_xor(s, 32, 64);
        if (lane < 16) {
          const int cc = col0 + wn * 64 + n * 16 + lane - C_;  // 0..511
          atomicAdd(&ksum[(size_t)((b << 3) + (cc >> 6)) * 64 + (cc & 63)], s);
        }
      }
    }
  } else {
    float* Cf = (float*)Cout;
#pragma unroll
    for (int m = 0; m < 8; m++) {
      const int r0 = row0 + wm * 128 + m * 16 + fg * 4;
#pragma unroll
      for (int n = 0; n < 4; n++) {
        const int c = col0 + wn * 64 + n * 16 + fr;
        const float bb = bias[c];
#pragma unroll
        for (int r = 0; r < 4; r++)
          Cf[(size_t)(r0 + r) * N + c] = acc[m][n][r] + bb;
      }
    }
  }
}

// ---------------------------------------------------------------- KV^T via MFMA
// KVT[bh][f][e] += sum_{n in chunk} v[n][f] * k_[n][e]
// grid: 128 bh * 8 chunks; block 256 (4 waves); wave w owns f-rows [16w,16w+16)
__global__ __launch_bounds__(256) void kv_mfma(const unsigned short* __restrict__ qkv,
                                               float* __restrict__ KVT) {
  const int bid = blockIdx.x;
  const int ch = bid & 7, bh = bid >> 3;
  const int h = bh & 7, b = bh >> 3;
  const int n0 = ch << 9;  // 512-row chunk
  __shared__ unsigned short ktile[64][68];
  __shared__ unsigned short vtile[64][68];
  const int tid = threadIdx.x;
  const int lane = tid & 63, w = tid >> 6;
  const int fr = lane & 15, fg = lane >> 4;
  const int srow = tid >> 3;            // 0..31
  const int sseg = (tid & 7) << 3;      // 0..56 step 8
  const unsigned short* gk = qkv + (size_t)(b * N_SEQ + n0 + srow) * QKVN + C_ + h * E_ + sseg;
  const unsigned short* gv = gk + C_;   // v is +512 elems within the row

  f32x4 acc[4] = {};
  short8 pk0, pk1, pv0, pv1;
  pk0 = *(const short8*)gk;
  pk1 = *(const short8*)(gk + (size_t)32 * QKVN);
  pv0 = *(const short8*)gv;
  pv1 = *(const short8*)(gv + (size_t)32 * QKVN);

  for (int it = 0; it < 8; ++it) {
    {
      s16x4* dk0 = (s16x4*)&ktile[srow][sseg];
      s16x4* dk1 = (s16x4*)&ktile[srow + 32][sseg];
      s16x4* dv0 = (s16x4*)&vtile[srow][sseg];
      s16x4* dv1 = (s16x4*)&vtile[srow + 32][sseg];
      const s16x4* s;
      s = (const s16x4*)&pk0; dk0[0] = s[0]; dk0[1] = s[1];
      s = (const s16x4*)&pk1; dk1[0] = s[0]; dk1[1] = s[1];
      s = (const s16x4*)&pv0; dv0[0] = s[0]; dv0[1] = s[1];
      s = (const s16x4*)&pv1; dv1[0] = s[0]; dv1[1] = s[1];
    }
    __syncthreads();
    if (it < 7) {
      const unsigned short* nk = gk + (size_t)(it + 1) * 64 * QKVN;
      const unsigned short* nv = gv + (size_t)(it + 1) * 64 * QKVN;
      pk0 = *(const short8*)nk;
      pk1 = *(const short8*)(nk + (size_t)32 * QKVN);
      pv0 = *(const short8*)nv;
      pv1 = *(const short8*)(nv + (size_t)32 * QKVN);
    }
#pragma unroll
    for (int ks = 0; ks < 2; ++ks) {
      const int kb = ks * 32;
      short8 av, bk0, bk1, bk2, bk3;
#pragma unroll
      for (int j = 0; j < 8; ++j) {
        const int row = kb + fg * 8 + j;
        av[j]  = (short)vtile[row][w * 16 + fr];
        bk0[j] = (short)ktile[row][fr];
        bk1[j] = (short)ktile[row][16 + fr];
        bk2[j] = (short)ktile[row][32 + fr];
        bk3[j] = (short)ktile[row][48 + fr];
      }
      acc[0] = __builtin_amdgcn_mfma_f32_16x16x32_bf16(av, bk0, acc[0], 0, 0, 0);
      acc[1] = __builtin_amdgcn_mfma_f32_16x16x32_bf16(av, bk1, acc[1], 0, 0, 0);
      acc[2] = __builtin_amdgcn_mfma_f32_16x16x32_bf16(av, bk2, acc[2], 0, 0, 0);
      acc[3] = __builtin_amdgcn_mfma_f32_16x16x32_bf16(av, bk3, acc[3], 0, 0, 0);
    }
    __syncthreads();
  }

  const size_t fbase = (size_t)bh * 64 + w * 16 + fg * 4;
#pragma unroll
  for (int e = 0; e < 4; ++e)
#pragma unroll
    for (int r = 0; r < 4; ++r)
      atomicAdd(&KVT[(fbase + r) * 64 + e * 16 + fr], acc[e][r]);
}

// ---------------------------------------------------------------- attention output
__global__ __launch_bounds__(256) void attn_out(const unsigned short* __restrict__ qkv,
                                                const float* __restrict__ KVT,
                                                const float* __restrict__ ksum,
                                                unsigned short* __restrict__ hout) {
  const int bid = blockIdx.x;
  const int nc = bid & 63, bh = bid >> 6;
  const int h = bh & 7, b = bh >> 3;
  const int n0 = nc << 6;  // 64-row chunk
  __shared__ float qs[64][68];
  __shared__ float denp[64][4];
  __shared__ float zl[64];
  __shared__ float kss[64];
  const int t = threadIdx.x;

#pragma unroll
  for (int half = 0; half < 2; half++) {
    const int row = (t >> 3) + half * 32;
    const int e0 = (t & 7) * 8;
    const unsigned short* srcq = qkv + (size_t)(b * N_SEQ + n0 + row) * QKVN + h * E_ + e0;
    short8 raw = *(const short8*)srcq;
#pragma unroll
    for (int i = 0; i < 8; i++) qs[row][e0 + i] = bf2f((unsigned short)raw[i]);
  }
  if (t < 64) kss[t] = ksum[bh * 64 + t];
  __syncthreads();

  {
    const int r = t >> 2, qp = t & 3;
    float s = 0.f;
#pragma unroll
    for (int e = 0; e < 16; e++) s = fmaf(qs[r][qp * 16 + e], kss[qp * 16 + e], s);
    denp[r][qp] = s;
  }
  __syncthreads();
  if (t < 64) zl[t] = 1.0f / (denp[t][0] + denp[t][1] + denp[t][2] + denp[t][3] + 1e-6f);
  __syncthreads();

  const int f = t & 63, rg = t >> 6;
  float kvc[64];
  const float* kvp = KVT + (size_t)bh * 4096 + (size_t)f * 64;
#pragma unroll
  for (int i = 0; i < 16; i++) {
    float4 v4 = *(const float4*)(kvp + i * 4);
    kvc[4 * i] = v4.x; kvc[4 * i + 1] = v4.y; kvc[4 * i + 2] = v4.z; kvc[4 * i + 3] = v4.w;
  }
#pragma unroll
  for (int i = 0; i < 16; i++) {
    const int row = rg * 16 + i;
    float a = 0.f;
#pragma unroll
    for (int e4 = 0; e4 < 16; e4++) {
      float4 qv = *(const float4*)&qs[row][e4 * 4];
      a = fmaf(qv.x, kvc[4 * e4 + 0], a);
      a = fmaf(qv.y, kvc[4 * e4 + 1], a);
      a = fmaf(qv.z, kvc[4 * e4 + 2], a);
      a = fmaf(qv.w, kvc[4 * e4 + 3], a);
    }
    const float val = a * zl[row];
    hout[(size_t)(b * N_SEQ + n0 + row) * C_ + h * E_ + f] = f2bf(val);
  }
}

// ---------------------------------------------------------------- launcher
extern "C" void kernel_launch(void* const* d_in, const int* in_sizes, int n_in,
                              void* d_out, int out_size, void* d_ws, size_t ws_size,
                              hipStream_t stream) {
  const float* x  = (const float*)d_in[0];
  const float* wq = (const float*)d_in[1];
  const float* wp = (const float*)d_in[2];
  const float* bp = (const float*)d_in[3];
  float* out = (float*)d_out;

  char* ws = (char*)d_ws;
  const size_t SZ_XBF  = (size_t)M_TOT * C_ * 2;      //  67108864
  const size_t SZ_QKV  = (size_t)M_TOT * QKVN * 2;    // 201326592
  const size_t SZ_WQ   = (size_t)QKVN * C_ * 2;       //   1572864
  const size_t SZ_WP   = (size_t)C_ * C_ * 2;         //    524288
  const size_t SZ_KVT  = (size_t)128 * 64 * 64 * 4;   //   2097152
  unsigned short* x_bf   = (unsigned short*)(ws);
  unsigned short* qkv_bf = (unsigned short*)(ws + SZ_XBF);
  unsigned short* wq_bf  = (unsigned short*)(ws + SZ_XBF + SZ_QKV);
  unsigned short* wp_bf  = (unsigned short*)(ws + SZ_XBF + SZ_QKV + SZ_WQ);
  float* KVT   = (float*)(ws + SZ_XBF + SZ_QKV + SZ_WQ + SZ_WP);
  float* ksumb = (float*)(ws + SZ_XBF + SZ_QKV + SZ_WQ + SZ_WP + SZ_KVT);
  unsigned short* hout = x_bf;  // reuse: x_bf dead after GEMM1

  (void)hipMemsetAsync(KVT, 0, SZ_KVT + 128 * 64 * 4, stream);

  cvt_bf16<<<16384, 256, 0, stream>>>(x, x_bf);
  cvt_bf16<<<384, 256, 0, stream>>>(wq, wq_bf);
  cvt_bf16<<<128, 256, 0, stream>>>(wp, wp_bf);

  gemm_bt<1><<<1536, 512, 0, stream>>>(x_bf, wq_bf, qkv_bf, nullptr, ksumb,
                                       M_TOT, QKVN, 6);
  kv_mfma<<<1024, 256, 0, stream>>>(qkv_bf, KVT);
  attn_out<<<8192, 256, 0, stream>>>(qkv_bf, KVT, ksumb, hout);
  gemm_bt<2><<<512, 512, 0, stream>>>(hout, wp_bf, out, bp, nullptr,
                                      M_TOT, C_, 2);
}